// Round 8
// baseline (794.439 us; speedup 1.0000x reference)
//
#include <hip/hip_runtime.h>

// CRF Viterbi decode: B=256, T=512, K=256, out (B, 514) as int32 tags.
//
// fwd: one block/batch, 16 waves. Wave w=(g,p): g=w>>1 owns i-rows
// [32g,32g+32), p=w&1 owns j-half; lane owns cols {j0,j0+1}, j0=128p+2*lane.
// Payload: 32 v2f over i from transT (TA=col j0, TB=col j1) — lives in
// AGPRs; reads are free as direct VALU operands (round-5 evidence: measured
// VALU == source inst count exactly). NO asm on payload operands (round-7's
// "v" constraints forced AGPR->VGPR copies). Scalar adds + asm v_max3_f32
// on add-results only: 96 compute insts/thread/step (1.5 per update).
// ONE raw s_barrier per step with lgkmcnt(0) only — NO vmcnt drain
// (__syncthreads would stall on same-step em prefetch + states stores).
// part[] double-buffered => single-barrier scheme is race-free:
//   st_w wave-private (in-order ds ops within wave);
//   fold(t) reads part[t&1], compute(t+1) writes part[(t+1)&1];
//   barrier(t+1) orders all writes of part[(t+1)&1] before fold(t+1).
// Fold: lanes<32, 8 b32 reads (<=2-way banks, free) + fmax + 3 max3.
// bwd: recompute backpointers via exact f32 equality scan (unchanged).
// ws: states[B*T*K] f32 (128 MiB) + transT[K*K] f32 (256 KiB).

#define TK 256
#define TT 512

typedef float v2f __attribute__((ext_vector_type(2)));
typedef float v4f __attribute__((ext_vector_type(4)));

__device__ __forceinline__ float max3f(float a, float b, float c) {
  float d;
  asm("v_max3_f32 %0, %1, %2, %3" : "=v"(d) : "v"(a), "v"(b), "v"(c));
  return d;
}

__global__ void transpose_kernel(const float* __restrict__ trans,
                                 float* __restrict__ transT) {
  int j = blockIdx.x;
  int i = threadIdx.x;
  transT[(size_t)j * TK + i] = trans[(size_t)i * TK + j];
}

#define K16(X) X(0) X(1) X(2) X(3) X(4) X(5) X(6) X(7) \
               X(8) X(9) X(10) X(11) X(12) X(13) X(14) X(15)

__global__ __launch_bounds__(1024)
__attribute__((amdgpu_waves_per_eu(4, 4)))
void crf_fwd(const float* __restrict__ em,
             const float* __restrict__ transT,
             const int* __restrict__ mask,
             float* __restrict__ states) {
  const int b = blockIdx.x;
  const int tid = threadIdx.x;
  const int lane = tid & 63;
  const int w = tid >> 6;    // wave 0..15
  const int g = w >> 1;      // i-rows [32g, 32g+32)
  const int p = w & 1;       // j-half
  const int j0 = 128 * p + 2 * lane;  // compute-phase cols {j0, j0+1}

  __shared__ __align__(16) float st_w[16][32];        // wave-private state
  __shared__ float part[2][8][2][2][64];              // dbuf partials, 16 KiB
  __shared__ int mk[TT];

  // payload: TA_n = {tr[32g+2n][j0], tr[32g+2n+1][j0]}, TB_n same for j0+1
  const float* ta = transT + (size_t)j0 * TK + 32 * g;
  const float* tbq = ta + TK;
#define TRD(n) \
  const v2f TA##n = *reinterpret_cast<const v2f*>(ta + 2 * (n)); \
  const v2f TB##n = *reinterpret_cast<const v2f*>(tbq + 2 * (n));
  K16(TRD)
#undef TRD

  if (tid < TT) mk[tid] = mask[(size_t)b * TT + tid];

  const size_t base = (size_t)b * TT * TK;
  // fold-phase constants (lanes<32 handle j = 32g + lane)
  const int pj = g >> 2;
  const int sel = lane & 1;
  const int col = 16 * (g & 3) + (lane >> 1);

  float ns = 0.f, e1 = 0.f, e2 = 0.f;
  if (lane < 32) {
    ns = em[base + 32 * g + lane];           // state0 = emissions[:,0,:]
    st_w[w][lane] = ns;
    if (p == 0) states[base + 32 * g + lane] = ns;
    e1 = em[base + TK + 32 * g + lane];      // em row 1
    e2 = em[base + 2 * TK + 32 * g + lane];  // em row 2
  }
  __syncthreads();  // mk + st_w init visible (full drain OK once)

  const float* emp = em + base + 3 * TK + 32 * g + lane;  // row t+2 at t=1
  float* stg = states + base + TK + 32 * g + lane;        // row t (p==0)
  const float* sw = st_w[w];

  for (int t = 1; t < TT; ++t) {
    // ---- compute phase: 8 uniform b128 state reads, 64 adds, 32 max3 ----
    const v4f S0 = reinterpret_cast<const v4f*>(sw)[0];
    const v4f S1 = reinterpret_cast<const v4f*>(sw)[1];
    const v4f S2 = reinterpret_cast<const v4f*>(sw)[2];
    const v4f S3 = reinterpret_cast<const v4f*>(sw)[3];
    const v4f S4 = reinterpret_cast<const v4f*>(sw)[4];
    const v4f S5 = reinterpret_cast<const v4f*>(sw)[5];
    const v4f S6 = reinterpret_cast<const v4f*>(sw)[6];
    const v4f S7 = reinterpret_cast<const v4f*>(sw)[7];

    float ax, ay;
    {
      const float c0 = S0.x + TA0.x, c1 = S0.y + TA0.y;
      ax = fmaxf(c0, c1);
      const float d0 = S0.x + TB0.x, d1 = S0.y + TB0.y;
      ay = fmaxf(d0, d1);
    }
#define STEP2(Sa, Sb, TAn, TBn)                                   \
    {                                                             \
      const float c0 = Sa + TAn.x, c1 = Sb + TAn.y;               \
      ax = max3f(ax, c0, c1);                                     \
      const float d0 = Sa + TBn.x, d1 = Sb + TBn.y;               \
      ay = max3f(ay, d0, d1);                                     \
    }
    STEP2(S0.z, S0.w, TA1, TB1)
    STEP2(S1.x, S1.y, TA2, TB2)
    STEP2(S1.z, S1.w, TA3, TB3)
    STEP2(S2.x, S2.y, TA4, TB4)
    STEP2(S2.z, S2.w, TA5, TB5)
    STEP2(S3.x, S3.y, TA6, TB6)
    STEP2(S3.z, S3.w, TA7, TB7)
    STEP2(S4.x, S4.y, TA8, TB8)
    STEP2(S4.z, S4.w, TA9, TB9)
    STEP2(S5.x, S5.y, TA10, TB10)
    STEP2(S5.z, S5.w, TA11, TB11)
    STEP2(S6.x, S6.y, TA12, TB12)
    STEP2(S6.z, S6.w, TA13, TB13)
    STEP2(S7.x, S7.y, TA14, TB14)
    STEP2(S7.z, S7.w, TA15, TB15)
#undef STEP2

    // two b32 part writes, banks = lane%32, 2 addrs/bank (free)
    float* pw = &part[t & 1][g][p][0][lane];
    pw[0] = ax;
    pw[64] = ay;

    // ---- single barrier: LDS-only wait, vmcnt stays in flight ----
    __builtin_amdgcn_sched_barrier(0);
    asm volatile("s_waitcnt lgkmcnt(0)" ::: "memory");
    __builtin_amdgcn_s_barrier();
    __builtin_amdgcn_sched_barrier(0);

    // ---- fold phase (lanes<32): j = 32g+lane ----
    if (lane < 32) {
      const float* pf = &part[t & 1][0][pj][sel][col];
      const float f0 = pf[0];
      const float f1 = pf[256];
      const float f2 = pf[512];
      const float f3 = pf[768];
      const float f4 = pf[1024];
      const float f5 = pf[1280];
      const float f6 = pf[1536];
      const float f7 = pf[1792];
      float f = max3f(fmaxf(f0, f1), f2, f3);
      f = max3f(f, f4, f5);
      f = max3f(f, f6, f7);
      ns = (mk[t] > 0) ? (f + e1) : ns;
      st_w[w][lane] = ns;
      if (p == 0) *stg = ns;
      stg += TK;
      e1 = e2;
      if (t + 2 < TT) e2 = *emp;
      emp += TK;
    }
  }
}

__device__ __forceinline__ float wave_max(float m) {
#pragma unroll
  for (int d = 1; d < 64; d <<= 1) m = fmaxf(m, __shfl_xor(m, d, 64));
  return m;
}

// First index i (lane-major: i = 4*lane + k) whose value equals m.
__device__ __forceinline__ int first_eq_idx(float s0, float s1, float s2,
                                            float s3, float m) {
  unsigned long long b0 = __ballot(s0 == m);
  unsigned long long b1 = __ballot(s1 == m);
  unsigned long long b2 = __ballot(s2 == m);
  unsigned long long b3 = __ballot(s3 == m);
  int best = 0x7fffffff;
  if (b0) best = min(best, 4 * (__ffsll(b0) - 1) + 0);
  if (b1) best = min(best, 4 * (__ffsll(b1) - 1) + 1);
  if (b2) best = min(best, 4 * (__ffsll(b2) - 1) + 2);
  if (b3) best = min(best, 4 * (__ffsll(b3) - 1) + 3);
  return best;
}

// Backward: one wave per batch; 511 serial steps. Recomputes the forward
// argmax exactly (f32 add/max bit-exact; first-occurrence tie-break).
__global__ __launch_bounds__(64, 1) void crf_bwd(const float* __restrict__ states,
                                                 const float* __restrict__ transT,
                                                 const int* __restrict__ mask,
                                                 int* __restrict__ out,
                                                 int out_stride) {
  const int b = blockIdx.x;
  const int lane = threadIdx.x;

  __shared__ int mk[TT];
  for (int q = lane; q < TT; q += 64) mk[q] = mask[(size_t)b * TT + q];
  __syncthreads();

  const size_t sbase = (size_t)b * TT * TK;
  int* outp = out + (size_t)b * out_stride;

  // zero the pad region (harness poisons d_out once)
  for (int q = TT + lane; q < out_stride; q += 64) outp[q] = 0;

  const float* srow = states + sbase;
  float4 r = *reinterpret_cast<const float4*>(srow + (size_t)(TT - 1) * TK + 4 * lane);
  float lm = fmaxf(fmaxf(r.x, r.y), fmaxf(r.z, r.w));
  lm = wave_max(lm);
  int tag = first_eq_idx(r.x, r.y, r.z, r.w, lm);

  auto LOADROW = [&](int rr) -> float4 {
    return *reinterpret_cast<const float4*>(srow + (size_t)rr * TK + 4 * lane);
  };
  float4 p0 = LOADROW(TT - 2), p1 = LOADROW(TT - 3), p2 = LOADROW(TT - 4),
         p3 = LOADROW(TT - 5);

  auto STEP = [&](float4 pr, int t) {
    int mkt = mk[t];
    if (lane == 0) outp[t] = (mkt > 0) ? tag : 0;  // tags * mask
    const float4 tv =
        *reinterpret_cast<const float4*>(transT + (size_t)tag * TK + 4 * lane);
    float s0 = pr.x + tv.x;
    float s1 = pr.y + tv.y;
    float s2 = pr.z + tv.z;
    float s3 = pr.w + tv.w;
    float m = fmaxf(fmaxf(s0, s1), fmaxf(s2, s3));
    m = wave_max(m);
    int prev = first_eq_idx(s0, s1, s2, s3, m);
    tag = (mkt > 0) ? prev : tag;
  };

  int t = TT - 1;
  while (t >= 4) {
    STEP(p0, t);     if (t - 5 >= 0) p0 = LOADROW(t - 5);
    STEP(p1, t - 1); if (t - 6 >= 0) p1 = LOADROW(t - 6);
    STEP(p2, t - 2); if (t - 7 >= 0) p2 = LOADROW(t - 7);
    STEP(p3, t - 3); if (t - 8 >= 0) p3 = LOADROW(t - 8);
    t -= 4;
  }
  STEP(p0, 3);
  STEP(p1, 2);
  STEP(p2, 1);
  if (lane == 0) outp[0] = (mk[0] > 0) ? tag : 0;
}

extern "C" void kernel_launch(void* const* d_in, const int* in_sizes, int n_in,
                              void* d_out, int out_size, void* d_ws, size_t ws_size,
                              hipStream_t stream) {
  const float* em = (const float*)d_in[0];
  const float* trans = (const float*)d_in[1];
  const int* mask = (const int*)d_in[2];
  int* out = (int*)d_out;

  const int B = in_sizes[0] / (TT * TK);      // 256
  const int out_stride = out_size / B;        // 514

  float* states = (float*)d_ws;
  float* transT = states + (size_t)B * TT * TK;

  transpose_kernel<<<TK, TK, 0, stream>>>(trans, transT);
  crf_fwd<<<B, 1024, 0, stream>>>(em, transT, mask, states);
  crf_bwd<<<B, 64, 0, stream>>>(states, transT, mask, out, out_stride);
}

// Round 10
// 794.296 us; speedup vs baseline: 1.0002x; 1.0002x over previous
//
#include <hip/hip_runtime.h>

// CRF Viterbi decode: B=256, T=512, K=256, out (B, 514) as int32 tags.
//
// ISA facts pinned by this session:
//  - v_add_f32 (VOP3) CAN read AGPR sources for free (r5: measured VALU ==
//    source inst count exactly, payload AGPR-resident).
//  - v_pk_add_f32 (VOP3P) CANNOT read AGPRs (r9 assembler reject).
//  - compiler never auto-fuses fmaxf pairs to v_max3_f32.
//
// fwd: one block/batch, 16 waves. Wave w=(g,p): g=w>>1 owns i-rows
// [32g,32g+32), p=w&1 owns j-half; lane owns cols {j0,j0+1}, j0=128p+2*lane.
// Payload: 32 v2f over i from transT (AGPR-resident, reads free).
// Inner: plain-C adds + TIED-operand asm v_max3_f32 ("+v" accumulator:
// out reg == in reg, no moves; inputs are fresh add results in VGPRs).
// ONE raw s_barrier per step, lgkmcnt(0)-only wait (vmcnt stays in flight),
// NO sched_barrier (order-pinning damage, m141). part[] double-buffered.
// bwd fused as tail (wave 0): recompute backpointers via exact f32
// equality scan (add/max bit-exact, first-occurrence tie-break).
// ws: states[B*T*K] f32 (128 MiB) + transT[K*K] f32 (256 KiB).

#define TK 256
#define TT 512

typedef float v2f __attribute__((ext_vector_type(2)));
typedef float v4f __attribute__((ext_vector_type(4)));

__device__ __forceinline__ void max3acc(float& acc, float a, float b) {
  asm("v_max3_f32 %0, %0, %1, %2" : "+v"(acc) : "v"(a), "v"(b));
}

__global__ void transpose_kernel(const float* __restrict__ trans,
                                 float* __restrict__ transT) {
  int j = blockIdx.x;
  int i = threadIdx.x;
  transT[(size_t)j * TK + i] = trans[(size_t)i * TK + j];
}

__device__ __forceinline__ float wave_max(float m) {
#pragma unroll
  for (int d = 1; d < 64; d <<= 1) m = fmaxf(m, __shfl_xor(m, d, 64));
  return m;
}

// First index i (lane-major: i = 4*lane + k) whose value equals m.
__device__ __forceinline__ int first_eq_idx(float s0, float s1, float s2,
                                            float s3, float m) {
  unsigned long long b0 = __ballot(s0 == m);
  unsigned long long b1 = __ballot(s1 == m);
  unsigned long long b2 = __ballot(s2 == m);
  unsigned long long b3 = __ballot(s3 == m);
  int best = 0x7fffffff;
  if (b0) best = min(best, 4 * (__ffsll(b0) - 1) + 0);
  if (b1) best = min(best, 4 * (__ffsll(b1) - 1) + 1);
  if (b2) best = min(best, 4 * (__ffsll(b2) - 1) + 2);
  if (b3) best = min(best, 4 * (__ffsll(b3) - 1) + 3);
  return best;
}

__global__ __launch_bounds__(1024)
__attribute__((amdgpu_waves_per_eu(4, 4)))
void crf_fused(const float* __restrict__ em,
               const float* __restrict__ transT,
               const int* __restrict__ mask,
               float* __restrict__ states,
               int* __restrict__ out,
               int out_stride) {
  const int b = blockIdx.x;
  const int tid = threadIdx.x;
  const int lane = tid & 63;
  const int w = tid >> 6;    // wave 0..15
  const int g = w >> 1;      // i-rows [32g, 32g+32)
  const int p = w & 1;       // j-half
  const int j0 = 128 * p + 2 * lane;  // compute-phase cols {j0, j0+1}

  __shared__ __align__(16) float st_w[16][32];        // wave-private state
  __shared__ float part[2][8][2][2][64];              // dbuf partials, 16 KiB
  __shared__ int mk[TT];

  // payload: TA_n = {tr[32g+2n][j0], tr[32g+2n+1][j0]}, TB_n same for j0+1
  const float* ta = transT + (size_t)j0 * TK + 32 * g;
  const float* tbq = ta + TK;
#define K16(X) X(0) X(1) X(2) X(3) X(4) X(5) X(6) X(7) \
               X(8) X(9) X(10) X(11) X(12) X(13) X(14) X(15)
#define TRD(n) \
  const v2f TA##n = *reinterpret_cast<const v2f*>(ta + 2 * (n)); \
  const v2f TB##n = *reinterpret_cast<const v2f*>(tbq + 2 * (n));
  K16(TRD)
#undef TRD
#undef K16

  if (tid < TT) mk[tid] = mask[(size_t)b * TT + tid];

  const size_t base = (size_t)b * TT * TK;
  // fold-phase constants (lanes<32 handle j = 32g + lane)
  const int pj = g >> 2;
  const int sel = lane & 1;
  const int col = 16 * (g & 3) + (lane >> 1);

  float ns = 0.f, e1 = 0.f, e2 = 0.f;
  if (lane < 32) {
    ns = em[base + 32 * g + lane];           // state0 = emissions[:,0,:]
    st_w[w][lane] = ns;
    if (p == 0) states[base + 32 * g + lane] = ns;
    e1 = em[base + TK + 32 * g + lane];      // em row 1
    e2 = em[base + 2 * TK + 32 * g + lane];  // em row 2
  }
  __syncthreads();  // mk + st_w init visible (full drain OK once)

  const float* emp = em + base + 3 * TK + 32 * g + lane;  // row t+2 at t=1
  float* stg = states + base + TK + 32 * g + lane;        // row t (p==0)
  const float* sw = st_w[w];

  for (int t = 1; t < TT; ++t) {
    // ---- compute: 8 uniform b128 reads, 64 adds, 32 tied max3 ----
    const v4f* swq = reinterpret_cast<const v4f*>(sw);
    const v4f S0 = swq[0];
    const v4f S1 = swq[1];
    const v4f S2 = swq[2];
    const v4f S3 = swq[3];
    const v4f S4 = swq[4];
    const v4f S5 = swq[5];
    const v4f S6 = swq[6];
    const v4f S7 = swq[7];

    float ax, ay;
    {
      const float c0 = S0.x + TA0.x, c1 = S0.y + TA0.y;
      ax = fmaxf(c0, c1);
      const float d0 = S0.x + TB0.x, d1 = S0.y + TB0.y;
      ay = fmaxf(d0, d1);
    }
#define STEP2(Sa, Sb, TAn, TBn)                                   \
    {                                                             \
      const float c0 = Sa + TAn.x, c1 = Sb + TAn.y;               \
      max3acc(ax, c0, c1);                                        \
      const float d0 = Sa + TBn.x, d1 = Sb + TBn.y;               \
      max3acc(ay, d0, d1);                                        \
    }
    STEP2(S0.z, S0.w, TA1, TB1)
    STEP2(S1.x, S1.y, TA2, TB2)
    STEP2(S1.z, S1.w, TA3, TB3)
    STEP2(S2.x, S2.y, TA4, TB4)
    STEP2(S2.z, S2.w, TA5, TB5)
    STEP2(S3.x, S3.y, TA6, TB6)
    STEP2(S3.z, S3.w, TA7, TB7)
    STEP2(S4.x, S4.y, TA8, TB8)
    STEP2(S4.z, S4.w, TA9, TB9)
    STEP2(S5.x, S5.y, TA10, TB10)
    STEP2(S5.z, S5.w, TA11, TB11)
    STEP2(S6.x, S6.y, TA12, TB12)
    STEP2(S6.z, S6.w, TA13, TB13)
    STEP2(S7.x, S7.y, TA14, TB14)
    STEP2(S7.z, S7.w, TA15, TB15)
#undef STEP2

    // two b32 part writes, banks = lane%32, 2-way (free)
    float* pw = &part[t & 1][g][p][0][lane];
    pw[0] = ax;
    pw[64] = ay;

    // ---- single barrier: LDS-only wait, vmcnt stays in flight ----
    asm volatile("s_waitcnt lgkmcnt(0)" ::: "memory");
    __builtin_amdgcn_s_barrier();

    // ---- fold phase (lanes<32): j = 32g+lane ----
    if (lane < 32) {
      const float* pf = &part[t & 1][0][pj][sel][col];
      const float f0 = pf[0];
      const float f1 = pf[256];
      const float f2 = pf[512];
      const float f3 = pf[768];
      const float f4 = pf[1024];
      const float f5 = pf[1280];
      const float f6 = pf[1536];
      const float f7 = pf[1792];
      float f = fmaxf(f0, f1);
      max3acc(f, f2, f3);
      max3acc(f, f4, f5);
      max3acc(f, f6, f7);
      ns = (mk[t] > 0) ? (f + e1) : ns;
      st_w[w][lane] = ns;
      if (p == 0) *stg = ns;
      stg += TK;
      e1 = e2;
      if (t + 2 < TT) e2 = *emp;
      emp += TK;
    }
  }

  // ===== backward tail (wave 0 only) =====
  __threadfence_block();
  __syncthreads();  // all states stores drained & visible block-wide
  if (w != 0) return;

  const size_t sbase = base;
  int* outp = out + (size_t)b * out_stride;
  for (int q = TT + lane; q < out_stride; q += 64) outp[q] = 0;  // pad

  const float* srow = states + sbase;
  float4 r = *reinterpret_cast<const float4*>(srow + (size_t)(TT - 1) * TK + 4 * lane);
  float lm = fmaxf(fmaxf(r.x, r.y), fmaxf(r.z, r.w));
  lm = wave_max(lm);
  int tag = first_eq_idx(r.x, r.y, r.z, r.w, lm);

  auto LOADROW = [&](int rr) -> float4 {
    return *reinterpret_cast<const float4*>(srow + (size_t)rr * TK + 4 * lane);
  };
  float4 p0 = LOADROW(TT - 2), p1 = LOADROW(TT - 3), p2 = LOADROW(TT - 4),
         p3 = LOADROW(TT - 5);

  auto STEP = [&](float4 pr, int t) {
    int mkt = mk[t];
    if (lane == 0) outp[t] = (mkt > 0) ? tag : 0;  // tags * mask
    const float4 tv =
        *reinterpret_cast<const float4*>(transT + (size_t)tag * TK + 4 * lane);
    float s0 = pr.x + tv.x;
    float s1 = pr.y + tv.y;
    float s2 = pr.z + tv.z;
    float s3 = pr.w + tv.w;
    float m = fmaxf(fmaxf(s0, s1), fmaxf(s2, s3));
    m = wave_max(m);
    int prev = first_eq_idx(s0, s1, s2, s3, m);
    tag = (mkt > 0) ? prev : tag;
  };

  int t = TT - 1;
  while (t >= 4) {
    STEP(p0, t);     if (t - 5 >= 0) p0 = LOADROW(t - 5);
    STEP(p1, t - 1); if (t - 6 >= 0) p1 = LOADROW(t - 6);
    STEP(p2, t - 2); if (t - 7 >= 0) p2 = LOADROW(t - 7);
    STEP(p3, t - 3); if (t - 8 >= 0) p3 = LOADROW(t - 8);
    t -= 4;
  }
  STEP(p0, 3);
  STEP(p1, 2);
  STEP(p2, 1);
  if (lane == 0) outp[0] = (mk[0] > 0) ? tag : 0;
}

extern "C" void kernel_launch(void* const* d_in, const int* in_sizes, int n_in,
                              void* d_out, int out_size, void* d_ws, size_t ws_size,
                              hipStream_t stream) {
  const float* em = (const float*)d_in[0];
  const float* trans = (const float*)d_in[1];
  const int* mask = (const int*)d_in[2];
  int* out = (int*)d_out;

  const int B = in_sizes[0] / (TT * TK);      // 256
  const int out_stride = out_size / B;        // 514

  float* states = (float*)d_ws;
  float* transT = states + (size_t)B * TT * TK;

  transpose_kernel<<<TK, TK, 0, stream>>>(trans, transT);
  crf_fused<<<B, 1024, 0, stream>>>(em, transT, mask, states, out, out_stride);
}